// Round 9
// baseline (931.648 us; speedup 1.0000x reference)
//
#include <hip/hip_runtime.h>
#include <hip/hip_fp16.h>

#define H 181
#define T_LEN 1024
#define BB 16            // batch rows per block
#define NBLK 64          // 64 * 16 = 1024
#define NTHR 768         // 12 waves, 3 per SIMD
#define KT 6             // K tiles of 32 -> 192 >= 181
#define FRAG 512         // shorts per kt fragment (64 lanes x 8)
#define JP 192           // padded hidden dim
#define XST 1058         // x_s row stride

typedef _Float16 half8 __attribute__((ext_vector_type(8)));
typedef __attribute__((ext_vector_type(4))) float floatx4;
typedef __attribute__((ext_vector_type(2))) float floatx2;

#define LOG2E 1.4426950408889634f

// Schraudolph exp2 (balanced sawtooth, |rel err| <= ~3%), clamped
#define SCH_C  1064992506.0f   // (127 - 0.043) * 2^23
#define SCH_LO 897220352.0f    // g = -20  -> e = 2^-20 (sigma -> 1)
#define SCH_HI 1182433024.0f   // g = +14  -> e ~ 2^14  (sigma -> 0; product-safe)

__device__ __forceinline__ float exp2_fast(float g) {
    float s = fmaf(g, 8388608.0f, SCH_C);
    s = fminf(fmaxf(s, SCH_LO), SCH_HI);       // folds to v_med3_f32
    return __uint_as_float((unsigned)s);
}
__device__ __forceinline__ float rcpf(float x) { return __builtin_amdgcn_rcpf(x); }
__device__ __forceinline__ float exp2f_hw(float x) { return __builtin_amdgcn_exp2f(x); }

// invert 4 positive denominators with one v_rcp (3 + 6 mul walkback)
__device__ __forceinline__ void inv4(const float d[4], float inv[4]) {
    float p1 = d[0] * d[1];
    float p2 = p1 * d[2];
    float p3 = p2 * d[3];
    float qv = rcpf(p3);
    inv[3] = qv * p2;  qv *= d[3];
    inv[2] = qv * p1;  qv *= d[2];
    inv[1] = qv * d[0];
    inv[0] = qv * d[1] * __builtin_amdgcn_rcpf(d[0] * d[1]) ; // placeholder (unused)
}

// 64 persistent blocks x 16 batch, 12 waves (3/SIMD).
// A = scaled w_hh (f16 regs, m = unit), B = h (f16 LDS, n = batch) in exact
// MFMA B-fragment order. GATE-MAJOR ordering: the 6 aR MFMAs issue first and
// sigma(r) computes while the aZ chain issues; sigma(z) overlaps the aN
// chain; only the n-gate tail is serial. This un-serializes the per-step
// [MFMA burst -> VALU burst] phase alternation (R8 post-mortem: pipes were
// 95% serialized). Math identical to R8 otherwise.
__launch_bounds__(NTHR, 3)
__global__ void gru_mfma(const float* __restrict__ x,
                         const float* __restrict__ w_ih,
                         const float* __restrict__ w_hh,
                         const float* __restrict__ b_ih,
                         const float* __restrict__ b_hh,
                         const float* __restrict__ w_fc,
                         const float* __restrict__ b_fc,
                         float* __restrict__ out) {
    __shared__ __align__(16) unsigned short hfr_s[2 * KT * FRAG];  // 24 KB dbuf (f16)
    __shared__ __align__(16) float x_s[16 * XST];                  // x [bb][t]; reused for FC

    const int tid  = threadIdx.x;
    const int wv   = tid >> 6;
    const int lane = tid & 63;
    const int col  = lane & 15;
    const int q    = lane >> 4;
    const int b0   = blockIdx.x * BB;
    const int jt   = wv;

    // ---- A fragments: scaled w_hh in f16 registers, [gate][kt] ----
    const int  mu = jt * 16 + col;
    const bool mv = (mu < H);
    const float gscale[3] = {-LOG2E, -LOG2E, 2.0f * LOG2E};
    half8 afr[3][KT];
    #pragma unroll
    for (int g = 0; g < 3; ++g) {
        const float* wrow = w_hh + (size_t)(g * H + (mv ? mu : 0)) * H;
        #pragma unroll
        for (int kt = 0; kt < KT; ++kt) {
            half8 f;
            #pragma unroll
            for (int e = 0; e < 8; ++e) {
                int k = kt * 32 + q * 8 + e;
                float v = (mv && k < H) ? gscale[g] * wrow[k] : 0.0f;
                f[e] = (_Float16)v;
            }
            afr[g][kt] = f;
        }
    }

    // ---- per-lane unit params (units j0..j0+3), log2e pre-folded, f32 ----
    const int j0 = jt * 16 + q * 4;
    float wrS[4], wzS[4], wnS[4], bnI[4];
    floatx4 seedR, seedZ, seedN;
    #pragma unroll
    for (int r = 0; r < 4; ++r) {
        int j = j0 + r;
        bool v = (j < H);
        wrS[r]  = v ? -LOG2E * w_ih[j]              : 0.0f;
        wzS[r]  = v ? -LOG2E * w_ih[H + j]          : 0.0f;
        wnS[r]  = v ?  2.0f * LOG2E * w_ih[2*H + j] : 0.0f;
        bnI[r]  = v ?  2.0f * LOG2E * b_ih[2*H + j] : 0.0f;
        seedR[r] = v ? -LOG2E * (b_ih[j] + b_hh[j])     : 0.0f;
        seedZ[r] = v ? -LOG2E * (b_ih[H+j] + b_hh[H+j]) : 0.0f;
        seedN[r] = v ?  2.0f * LOG2E * b_hh[2*H + j]    : 0.0f;
    }

    // ---- frag-slot address for this lane's h write ----
    const int wkt  = j0 >> 5;
    const int wq   = (j0 >> 3) & 3;
    const int we   = j0 & 7;
    const int woff = wkt * FRAG + (wq * 16 + col) * 8 + we;
    const int rbase = lane * 8;

    // ---- stage x coalesced into [bb][t] ----
    for (int i = tid; i < BB * T_LEN; i += NTHR) {
        int bb = i >> 10, t = i & 1023;
        x_s[bb * XST + t] = x[(size_t)b0 * T_LEN + i];
    }
    for (int i = tid; i < 2 * KT * FRAG; i += NTHR) hfr_s[i] = 0;
    __syncthreads();

    float h[4] = {0.f, 0.f, 0.f, 0.f};

    auto step = [&](const unsigned short* rb, unsigned short* wb, float xv) {
        half8 bfrg[KT];
        #pragma unroll
        for (int kt = 0; kt < KT; ++kt)
            bfrg[kt] = *(const half8*)&rb[kt * FRAG + rbase];

        // ---- R chain: 6 MFMAs, then sigma(r) (overlaps Z chain below) ----
        floatx4 aR = seedR;
        #pragma unroll
        for (int kt = 0; kt < KT; ++kt)
            aR = __builtin_amdgcn_mfma_f32_16x16x32_f16(afr[0][kt], bfrg[kt], aR, 0, 0, 0);

        float dR[4];
        #pragma unroll
        for (int r = 0; r < 4; ++r)
            dR[r] = 1.0f + exp2_fast(fmaf(xv, wrS[r], aR[r]));
        float pR1 = dR[0] * dR[1], pR2 = pR1 * dR[2], pR3 = pR2 * dR[3];
        float qR = rcpf(pR3);
        float invR[4];
        invR[3] = qR * pR2;  qR *= dR[3];
        invR[2] = qR * pR1;  qR *= dR[2];
        invR[1] = qR * dR[0];
        invR[0] = qR * dR[1];

        // ---- Z chain: 6 MFMAs, then sigma(z) (overlaps N chain below) ----
        floatx4 aZ = seedZ;
        #pragma unroll
        for (int kt = 0; kt < KT; ++kt)
            aZ = __builtin_amdgcn_mfma_f32_16x16x32_f16(afr[1][kt], bfrg[kt], aZ, 0, 0, 0);

        float dZ[4];
        #pragma unroll
        for (int r = 0; r < 4; ++r)
            dZ[r] = 1.0f + exp2_fast(fmaf(xv, wzS[r], aZ[r]));
        float pZ1 = dZ[0] * dZ[1], pZ2 = pZ1 * dZ[2], pZ3 = pZ2 * dZ[3];
        float qZ = rcpf(pZ3);
        float invZ[4];
        invZ[3] = qZ * pZ2;  qZ *= dZ[3];
        invZ[2] = qZ * pZ1;  qZ *= dZ[2];
        invZ[1] = qZ * dZ[0];
        invZ[0] = qZ * dZ[1];

        // ---- N chain: 6 MFMAs, then the serial tail ----
        floatx4 aN = seedN;
        #pragma unroll
        for (int kt = 0; kt < KT; ++kt)
            aN = __builtin_amdgcn_mfma_f32_16x16x32_f16(afr[2][kt], bfrg[kt], aN, 0, 0, 0);

        float dn[4];
        #pragma unroll
        for (int r = 0; r < 4; ++r) {
            float gn = fmaf(invR[r], aN[r], fmaf(xv, wnS[r], bnI[r]));
            dn[r] = 1.0f + exp2f_hw(fminf(gn, 30.0f));
        }
        float pn1 = dn[0] * dn[1], pn2 = pn1 * dn[2], pn3 = pn2 * dn[3];
        float qn = rcpf(pn3);
        float rn[4];
        rn[3] = qn * pn2;  qn *= dn[3];
        rn[2] = qn * pn1;  qn *= dn[2];
        rn[1] = qn * dn[0];
        rn[0] = qn * dn[1];

        #pragma unroll
        for (int r = 0; r < 4; ++r) {
            float nn = fmaf(-2.0f, rn[r], 1.0f);       // tanh
            h[r] = fmaf(invZ[r], h[r] - nn, nn);       // n + z*(h-n)
        }
        unsigned pk0 = __builtin_bit_cast(unsigned,
                           __builtin_amdgcn_cvt_pkrtz(h[0], h[1]));
        unsigned pk1 = __builtin_bit_cast(unsigned,
                           __builtin_amdgcn_cvt_pkrtz(h[2], h[3]));
        *(uint2*)&wb[woff] = make_uint2(pk0, pk1);
        __syncthreads();
    };

    const float* xrow = &x_s[col * XST];
    for (int t = 0; t < T_LEN; t += 2) {
        floatx2 xv2 = *(const floatx2*)&xrow[t];
        step(hfr_s,             hfr_s + KT * FRAG, xv2[0]);
        step(hfr_s + KT * FRAG, hfr_s,             xv2[1]);
    }

    // ---- final FC; reuse x_s as fp32 h buffer ----
    float* hfin = x_s;
    floatx4 hv = {h[0], h[1], h[2], h[3]};
    *(floatx4*)&hfin[col * JP + j0] = hv;
    __syncthreads();
    if (tid < BB * 10) {
        int bb = tid / 10, c = tid % 10;
        float acc = b_fc[c];
        for (int k = 0; k < H; ++k)
            acc = fmaf(hfin[bb * JP + k], w_fc[c * H + k], acc);
        out[(b0 + bb) * 10 + c] = acc;
    }
}

extern "C" void kernel_launch(void* const* d_in, const int* in_sizes, int n_in,
                              void* d_out, int out_size, void* d_ws, size_t ws_size,
                              hipStream_t stream) {
    const float* x    = (const float*)d_in[0];
    const float* w_ih = (const float*)d_in[1];
    const float* w_hh = (const float*)d_in[2];
    const float* b_ih = (const float*)d_in[3];
    const float* b_hh = (const float*)d_in[4];
    const float* w_fc = (const float*)d_in[5];
    const float* b_fc = (const float*)d_in[6];
    float* out = (float*)d_out;

    gru_mfma<<<NBLK, NTHR, 0, stream>>>(x, w_ih, w_hh, b_ih, b_hh, w_fc, b_fc, out);
}